// Round 7
// baseline (115.013 us; speedup 1.0000x reference)
//
#include <hip/hip_runtime.h>

// AdaptiveSparsityAttention on MI355X (gfx950).
// f32 in/out, internal bf16 MFMA; mask logits in f32-grade precision via
// algebraic fusion + split-bf16 (Ootomo) MFMA for the a/c GEMM.
//
// R7: - ac GEMM -> split-bf16 MFMA: x=xh+xl, Beff=Bh+Bl,
//       x@Beff ~= xh@Bh + xh@Bl + xl@Bh (residual ~2e-6, mask-safe).
//     - mask co-scheduled with qkv in ONE dispatch (MFMA || VALU, m114);
//       mask LDS h-chunked (32/chunk) to keep union 24KB.
// Order: prep -> ac -> qkvmask -> scores -> pv -> out  (6 launches).

typedef unsigned short u16t;
typedef __bf16 bf16x8 __attribute__((ext_vector_type(8)));
typedef float f32x4 __attribute__((ext_vector_type(4)));

#define B_SZ 2
#define S_SZ 1024
#define D_SZ 512
#define DH 256
#define HH 128   // hidden dim of sparsity predictor

static __device__ __forceinline__ u16t f2b(float f) {
    unsigned int u = __builtin_bit_cast(unsigned int, f);
    u += 0x7FFFu + ((u >> 16) & 1u);
    return (u16t)(u >> 16);
}
static __device__ __forceinline__ float b2f(u16t u) {
    return __builtin_bit_cast(float, (unsigned int)u << 16);
}

static __device__ __forceinline__ f32x4 mfma16(bf16x8 a, bf16x8 b, f32x4 c) {
    return __builtin_amdgcn_mfma_f32_16x16x32_bf16(a, b, c, 0, 0, 0);
}

static __device__ __forceinline__ void gload16(const void* g, void* l) {
    __builtin_amdgcn_global_load_lds(
        (const __attribute__((address_space(1))) void*)g,
        (__attribute__((address_space(3))) void*)l, 16, 0, 0);
}

// ---------------------------------------------------------- K0: fused prep
// blocks [0,1024): x->xb,xl | [1024,2048): W transposes | [2048,2560): Beff
__global__ __launch_bounds__(256) void k_prep(
    const float* __restrict__ x,
    const float* __restrict__ Wq, const float* __restrict__ Wk,
    const float* __restrict__ Wv, const float* __restrict__ Wo,
    const float* __restrict__ W1,
    u16t* __restrict__ xb, u16t* __restrict__ xl,
    u16t* __restrict__ WT, float* __restrict__ Beff)
{
    __shared__ float smf[1088];   // union: tile[32][33] (trans) | wm[2][256] (eff)
    int bidx = blockIdx.x;
    int t = threadIdx.x;
    if (bidx < 1024) {
        int idx = (bidx * 256 + t) * 4;
        float4 v = *(const float4*)(x + idx);
        u16t h[4], l[4];
        h[0] = f2b(v.x); h[1] = f2b(v.y); h[2] = f2b(v.z); h[3] = f2b(v.w);
        l[0] = f2b(v.x - b2f(h[0])); l[1] = f2b(v.y - b2f(h[1]));
        l[2] = f2b(v.z - b2f(h[2])); l[3] = f2b(v.w - b2f(h[3]));
        *(ushort4*)(xb + idx) = *(ushort4*)h;
        *(ushort4*)(xl + idx) = *(ushort4*)l;
    } else if (bidx < 2048) {
        int t2 = bidx - 1024;
        int z = t2 >> 8, rem = t2 & 255;
        int n0 = (rem & 15) * 32, k0 = (rem >> 4) * 32;
        const float* W = z == 0 ? Wq : z == 1 ? Wk : z == 2 ? Wv : Wo;
        u16t* WTz = WT + (size_t)z * D_SZ * D_SZ;
        float (*tile)[33] = (float(*)[33])smf;
        int r = t >> 3, c4 = (t & 7) * 4;
        float4 v = *(const float4*)(W + (size_t)(k0 + r) * D_SZ + n0 + c4);
        tile[r][c4] = v.x; tile[r][c4 + 1] = v.y; tile[r][c4 + 2] = v.z; tile[r][c4 + 3] = v.w;
        __syncthreads();
        u16t o[4];
        o[0] = f2b(tile[c4][r]); o[1] = f2b(tile[c4 + 1][r]);
        o[2] = f2b(tile[c4 + 2][r]); o[3] = f2b(tile[c4 + 3][r]);
        *(ushort4*)(WTz + (size_t)(n0 + r) * D_SZ + k0 + c4) = *(ushort4*)o;
    } else {
        int k = bidx - 2048;   // 0..511
        float* wm0 = smf;
        float* wm1 = smf + 256;
        const float* wrq = Wq + (size_t)k * D_SZ;
        const float* wrk = Wk + (size_t)k * D_SZ;
        wm0[t & 255] = 0.5f * (wrq[t & 255] + wrq[(t & 255) + DH]);
        wm1[t & 255] = 0.5f * (wrk[t & 255] + wrk[(t & 255) + DH]);
        __syncthreads();
        int half = t >> 7, hcol = t & 127;
        const float* wm = half ? wm1 : wm0;
        const float* W1h = W1 + (half ? (size_t)DH * HH : 0);
        float s = 0.f;
        for (int d = 0; d < 256; ++d) s += wm[d] * W1h[(size_t)d * HH + hcol];
        Beff[(size_t)k * 256 + half * 128 + hcol] = s;
    }
}

// ------------------------------------------------------------- GEMM mainloop
// C[BM=128][BN=NF*16] per block (256 thr, 4 waves; wave w owns rows w*32..+32).
// LDS: linear Als[128][64], Bls[NF*16][64] u16, staged via global_load_lds.
template<int NF>
static __device__ __forceinline__ void gemm_mainloop(
    const u16t* __restrict__ A, int lda, const u16t* __restrict__ B, int ldb,
    int K, int tid, u16t* Als, u16t* Bls, f32x4 acc[2][NF])
{
    const int w = tid >> 6, lane = tid & 63;
    const int lr = lane & 15, kg = lane >> 4;
    const int srow = lane >> 3, scol = (lane & 7) * 8;
    for (int k0 = 0; k0 < K; k0 += 64) {
        if (k0) __syncthreads();
#pragma unroll
        for (int q = 0; q < 4; ++q) {
            int ci = w * 4 + q;
            gload16(A + (size_t)(ci * 8 + srow) * lda + k0 + scol, Als + ci * 512);
        }
#pragma unroll
        for (int q = 0; q < NF / 2; ++q) {
            int cj = w * (NF / 2) + q;
            gload16(B + (size_t)(cj * 8 + srow) * ldb + k0 + scol, Bls + cj * 512);
        }
        __syncthreads();
#pragma unroll
        for (int kk = 0; kk < 2; ++kk) {
            bf16x8 af[2], bfr[NF];
#pragma unroll
            for (int fi = 0; fi < 2; ++fi)
                af[fi] = *(const bf16x8*)(&Als[(w * 32 + fi * 16 + lr) * 64 + kk * 32 + kg * 8]);
#pragma unroll
            for (int fj = 0; fj < NF; ++fj)
                bfr[fj] = *(const bf16x8*)(&Bls[(fj * 16 + lr) * 64 + kk * 32 + kg * 8]);
#pragma unroll
            for (int fi = 0; fi < 2; ++fi)
#pragma unroll
                for (int fj = 0; fj < NF; ++fj)
                    acc[fi][fj] = mfma16(af[fi], bfr[fj], acc[fi][fj]);
        }
    }
}

// C-frag element (fi,fj,rr): row = m0+w*32+fi*16+kg*4+rr, col = n0+fj*16+lr  [m89-verified]

// ------------------------- K1: [a|c] = x @ Beff via split-bf16 MFMA
// BM=128, BN=32, K=512. acc = xh@Bh + xh@Bl + xl@Bh (f32 acc). grid (16,8).
__global__ __launch_bounds__(256) void k_ac(
    const u16t* __restrict__ xb, const u16t* __restrict__ xl,
    const float* __restrict__ Beff, const float* __restrict__ b1,
    float* __restrict__ a, float* __restrict__ cc)
{
    __shared__ u16t Ah[128 * 64];   // 16KB
    __shared__ u16t Alo[128 * 64];  // 16KB
    __shared__ u16t Bh[32 * 72];    // 4.5KB (pad 72 keeps b128 reads 16B-aligned)
    __shared__ u16t Bl[32 * 72];
    int m0 = blockIdx.x * 128, n0 = blockIdx.y * 32;
    int t = threadIdx.x;
    const int w = t >> 6, lane = t & 63, lr = lane & 15, kg = lane >> 4;
    const int srow = lane >> 3, scol = (lane & 7) * 8;
    f32x4 acc[2][2] = {};
    for (int k0 = 0; k0 < 512; k0 += 64) {
        if (k0) __syncthreads();
#pragma unroll
        for (int q = 0; q < 4; ++q) {
            int ci = w * 4 + q;
            gload16(xb + (size_t)(m0 + ci * 8 + srow) * D_SZ + k0 + scol, Ah + ci * 512);
            gload16(xl + (size_t)(m0 + ci * 8 + srow) * D_SZ + k0 + scol, Alo + ci * 512);
        }
        {   // B: load Beff f32 [k0..+64][n0..+32], split hi/lo, transpose to [n][k]
            int nn = t & 31, kq = t >> 5;
#pragma unroll
            for (int p = 0; p < 8; ++p) {
                int k = kq + p * 8;
                float v = Beff[(size_t)(k0 + k) * 256 + n0 + nn];
                u16t hi = f2b(v);
                Bh[nn * 72 + k] = hi;
                Bl[nn * 72 + k] = f2b(v - b2f(hi));
            }
        }
        __syncthreads();
#pragma unroll
        for (int kk = 0; kk < 2; ++kk) {
            bf16x8 ah[2], al2[2], bh[2], bl2[2];
#pragma unroll
            for (int fi = 0; fi < 2; ++fi) {
                ah[fi]  = *(const bf16x8*)(&Ah [(w * 32 + fi * 16 + lr) * 64 + kk * 32 + kg * 8]);
                al2[fi] = *(const bf16x8*)(&Alo[(w * 32 + fi * 16 + lr) * 64 + kk * 32 + kg * 8]);
            }
#pragma unroll
            for (int fj = 0; fj < 2; ++fj) {
                bh[fj]  = *(const bf16x8*)(&Bh[(fj * 16 + lr) * 72 + kk * 32 + kg * 8]);
                bl2[fj] = *(const bf16x8*)(&Bl[(fj * 16 + lr) * 72 + kk * 32 + kg * 8]);
            }
#pragma unroll
            for (int fi = 0; fi < 2; ++fi)
#pragma unroll
                for (int fj = 0; fj < 2; ++fj) {
                    acc[fi][fj] = mfma16(ah[fi],  bh[fj],  acc[fi][fj]);
                    acc[fi][fj] = mfma16(ah[fi],  bl2[fj], acc[fi][fj]);
                    acc[fi][fj] = mfma16(al2[fi], bh[fj],  acc[fi][fj]);
                }
        }
    }
    bool isA = n0 < 128;
#pragma unroll
    for (int fi = 0; fi < 2; ++fi)
#pragma unroll
        for (int fj = 0; fj < 2; ++fj) {
            int col = n0 + fj * 16 + lr;
            float badd = isA ? b1[col] : 0.f;
#pragma unroll
            for (int rr = 0; rr < 4; ++rr) {
                int row = m0 + w * 32 + fi * 16 + kg * 4 + rr;
                if (isA) a[(size_t)row * HH + col] = acc[fi][fj][rr] + badd;
                else     cc[(size_t)row * HH + (col - 128)] = acc[fi][fj][rr];
            }
        }
}

// ----------------------- K2: fused QKV GEMMs (MFMA) + mask bits (VALU)
// 1D grid, 896 blocks: [0,384) -> qkv (z = bid/128); [384,896) -> mask.
// LDS union: qkv 24KB | mask ~19KB (h-chunked 32). MFMA and VALU co-schedule.
__global__ __launch_bounds__(256) void k_qkvmask(
    const u16t* __restrict__ xb, const u16t* __restrict__ WT,
    const float* __restrict__ a, const float* __restrict__ c,
    const float* __restrict__ W2, const float* __restrict__ b2,
    u16t* __restrict__ qb, u16t* __restrict__ kb, u16t* __restrict__ vT,
    unsigned char* __restrict__ maskb)
{
    __shared__ __align__(16) char sm[24576];
    int bid = blockIdx.x;
    int t = threadIdx.x;
    if (bid < 384) {
        u16t* Als = (u16t*)sm;               // [128][64] = 16KB
        u16t* Bls = Als + 8192;              // [64][64]  = 8KB
        int z = bid / 128, rem = bid & 127;
        int m0 = (rem >> 3) * 128, n0 = (rem & 7) * 64;
        const u16t* A = xb + (size_t)m0 * D_SZ;
        const u16t* Bt = WT + (size_t)z * D_SZ * D_SZ + (size_t)n0 * D_SZ;
        f32x4 acc[2][4] = {};
        gemm_mainloop<4>(A, D_SZ, Bt, D_SZ, D_SZ, t, Als, Bls, acc);
        int w = t >> 6, lane = t & 63, lr = lane & 15, kg = lane >> 4;
        __syncthreads();
        if (z < 2) {
            u16t (*vls)[68] = (u16t(*)[68])sm;
            float scale = z == 0 ? 0.0625f : 1.0f;
#pragma unroll
            for (int fi = 0; fi < 2; ++fi)
#pragma unroll
                for (int fj = 0; fj < 4; ++fj)
#pragma unroll
                    for (int rr = 0; rr < 4; ++rr)
                        vls[w * 32 + fi * 16 + kg * 4 + rr][fj * 16 + lr]
                            = f2b(acc[fi][fj][rr] * scale);
            __syncthreads();
            u16t* dst = z == 0 ? qb : kb;
            int c8 = (t & 7) * 8, r0 = t >> 3;
#pragma unroll
            for (int p = 0; p < 4; ++p) {
                int r = r0 + p * 32;
                *(uint4*)(dst + (size_t)(m0 + r) * D_SZ + n0 + c8) = *(const uint4*)(&vls[r][c8]);
            }
        } else {
            u16t (*vls)[136] = (u16t(*)[136])sm;   // 64*136*2 = 17408
#pragma unroll
            for (int fi = 0; fi < 2; ++fi)
#pragma unroll
                for (int fj = 0; fj < 4; ++fj)
#pragma unroll
                    for (int rr = 0; rr < 4; ++rr)
                        vls[fj * 16 + lr][w * 32 + fi * 16 + kg * 4 + rr] = f2b(acc[fi][fj][rr]);
            __syncthreads();
            int b = m0 >> 10, s0 = m0 & 1023;
            int cr = t >> 2, seg = t & 3;
            const u16t* srcp = &vls[cr][seg * 32];
            u16t* dstp = vT + (((size_t)(b * D_SZ + n0 + cr)) << 10) + s0 + seg * 32;
#pragma unroll
            for (int qq = 0; qq < 4; ++qq)
                *(uint4*)(dstp + qq * 8) = *(const uint4*)(srcp + qq * 8);
        }
    } else {
        // mask: 64x64 (i,j) tile, 4x4/thread, h chunked by 32.
        float (*at)[36] = (float(*)[36])sm;            // 9216B
        float (*ct)[36] = (float(*)[36])(sm + 9216);   // 9216B
        float* w2s = (float*)(sm + 18432);             // 512B
        int t2 = bid - 384;                 // 0..511
        int b = t2 >> 8, rem = t2 & 255;
        int i0 = (rem >> 4) * 64, j0 = (rem & 15) * 64;
        if (t < 128) w2s[t] = W2[t];
        float fb2 = b2[0];
        int ti = t >> 4, tj = t & 15;
        float acc[4][4];
#pragma unroll
        for (int ri = 0; ri < 4; ++ri)
#pragma unroll
            for (int rj = 0; rj < 4; ++rj) acc[ri][rj] = fb2;
        int sr = t >> 2, sc = (t & 3) * 8;
        for (int hc = 0; hc < 4; ++hc) {
            __syncthreads();
            const float* ap = a + (size_t)(b * S_SZ + i0 + sr) * HH + hc * 32 + sc;
            const float* cp = c + (size_t)(b * S_SZ + j0 + sr) * HH + hc * 32 + sc;
            *(float4*)&at[sr][sc]     = *(const float4*)ap;
            *(float4*)&at[sr][sc + 4] = *(const float4*)(ap + 4);
            *(float4*)&ct[sr][sc]     = *(const float4*)cp;
            *(float4*)&ct[sr][sc + 4] = *(const float4*)(cp + 4);
            __syncthreads();
#pragma unroll
            for (int h4 = 0; h4 < 8; ++h4) {
                float4 wv = *(const float4*)&w2s[hc * 32 + h4 * 4];
                float4 av[4], cv[4];
#pragma unroll
                for (int ri = 0; ri < 4; ++ri) av[ri] = *(const float4*)&at[ti + 16 * ri][h4 * 4];
#pragma unroll
                for (int rj = 0; rj < 4; ++rj) cv[rj] = *(const float4*)&ct[tj + 16 * rj][h4 * 4];
#pragma unroll
                for (int ri = 0; ri < 4; ++ri)
#pragma unroll
                    for (int rj = 0; rj < 4; ++rj) {
                        acc[ri][rj] += fmaxf(av[ri].x + cv[rj].x, 0.f) * wv.x;
                        acc[ri][rj] += fmaxf(av[ri].y + cv[rj].y, 0.f) * wv.y;
                        acc[ri][rj] += fmaxf(av[ri].z + cv[rj].z, 0.f) * wv.z;
                        acc[ri][rj] += fmaxf(av[ri].w + cv[rj].w, 0.f) * wv.w;
                    }
            }
        }
#pragma unroll
        for (int ri = 0; ri < 4; ++ri)
#pragma unroll
            for (int rj = 0; rj < 4; ++rj) {
                int i = i0 + ti + 16 * ri, j = j0 + tj + 16 * rj;
                maskb[((size_t)b << 20) + ((size_t)i << 10) + j] = acc[ri][rj] > 0.f ? 1 : 0;
            }
    }
}

// ---------------------------- K3: P_unnorm = exp(masked QK^T) + row-sum partials
__global__ __launch_bounds__(256) void k_scores(
    const u16t* __restrict__ qb, const u16t* __restrict__ kb,
    const unsigned char* __restrict__ maskb, u16t* __restrict__ P,
    float* __restrict__ lpart)
{
    __shared__ __align__(16) u16t sm[12288];   // Als 16KB + Bls 8KB
    u16t* Als = sm;
    u16t* Bls = sm + 8192;
    int bh = blockIdx.z, b = bh >> 1, h = bh & 1;
    int jb = blockIdx.x;
    int m0 = blockIdx.y * 128, n0 = jb * 64;
    const u16t* A = qb + (size_t)b * S_SZ * D_SZ + (size_t)m0 * D_SZ + h * DH;
    const u16t* Bt = kb + (size_t)b * S_SZ * D_SZ + (size_t)n0 * D_SZ + h * DH;
    f32x4 acc[2][4] = {};
    gemm_mainloop<4>(A, D_SZ, Bt, D_SZ, DH, threadIdx.x, Als, Bls, acc);
    int w = threadIdx.x >> 6, lane = threadIdx.x & 63, lr = lane & 15, kg = lane >> 4;
#pragma unroll
    for (int fi = 0; fi < 2; ++fi)
#pragma unroll
        for (int rr = 0; rr < 4; ++rr) {
            int i = m0 + w * 32 + fi * 16 + kg * 4 + rr;
            float rs = 0.f;
#pragma unroll
            for (int fj = 0; fj < 4; ++fj) {
                int j = n0 + fj * 16 + lr;
                bool msk = maskb[((size_t)b << 20) + ((size_t)i << 10) + j] != 0;
                float e = msk ? __expf(acc[fi][fj][rr]) : 0.f;
                acc[fi][fj][rr] = e;
                rs += e;
            }
            rs += __shfl_xor(rs, 1); rs += __shfl_xor(rs, 2);
            rs += __shfl_xor(rs, 4); rs += __shfl_xor(rs, 8);
            if (lr == 0) lpart[((size_t)(jb * 4 + bh) << 10) + i] = rs;
        }
    __syncthreads();
    u16t (*vls)[68] = (u16t(*)[68])sm;
#pragma unroll
    for (int fi = 0; fi < 2; ++fi)
#pragma unroll
        for (int fj = 0; fj < 4; ++fj)
#pragma unroll
            for (int rr = 0; rr < 4; ++rr)
                vls[w * 32 + fi * 16 + kg * 4 + rr][fj * 16 + lr] = f2b(acc[fi][fj][rr]);
    __syncthreads();
    int c8 = (threadIdx.x & 7) * 8, r0 = threadIdx.x >> 3;
#pragma unroll
    for (int p = 0; p < 4; ++p) {
        int r = r0 + p * 32;
        *(uint4*)(P + ((size_t)bh << 20) + ((size_t)(m0 + r) << 10) + n0 + c8)
            = *(const uint4*)(&vls[r][c8]);
    }
}

// ------------------------------------------------- K4: PV (+ diag(1/l) epilogue)
__global__ __launch_bounds__(256) void k_pv(
    const u16t* __restrict__ P, const u16t* __restrict__ vT,
    const float* __restrict__ lpart, u16t* __restrict__ ao)
{
    __shared__ __align__(16) u16t sm[10240];   // Als 16KB + Bls 4KB
    __shared__ float invl[128];
    u16t* Als = sm;
    u16t* Bls = sm + 8192;
    int bh = blockIdx.z, b = bh >> 1, h = bh & 1;
    int m0 = blockIdx.y * 128, n0 = blockIdx.x * 32;
    int t = threadIdx.x;
    if (t < 128) {
        float l = 0.f;
        for (int jb = 0; jb < 16; ++jb)
            l += lpart[((size_t)(jb * 4 + bh) << 10) + m0 + t];
        invl[t] = l > 0.f ? 1.0f / l : 0.f;
    }
    const u16t* A = P + ((size_t)bh << 20) + (size_t)m0 * S_SZ;
    const u16t* Bt = vT + ((size_t)(b * D_SZ + h * DH + n0)) * S_SZ;
    f32x4 acc[2][2] = {};
    gemm_mainloop<2>(A, S_SZ, Bt, S_SZ, S_SZ, t, Als, Bls, acc);
    int w = t >> 6, lane = t & 63, lr = lane & 15, kg = lane >> 4;
    __syncthreads();
    u16t (*ols)[40] = (u16t(*)[40])sm;
#pragma unroll
    for (int fi = 0; fi < 2; ++fi) {
        int rl = w * 32 + fi * 16 + kg * 4;
#pragma unroll
        for (int fj = 0; fj < 2; ++fj)
#pragma unroll
            for (int rr = 0; rr < 4; ++rr)
                ols[rl + rr][fj * 16 + lr] = f2b(acc[fi][fj][rr] * invl[rl + rr]);
    }
    __syncthreads();
    int c8 = (t & 3) * 8, r0 = t >> 2;
#pragma unroll
    for (int p = 0; p < 2; ++p) {
        int r = r0 + p * 64;
        *(uint4*)(ao + ((size_t)(b * S_SZ + m0 + r)) * D_SZ + h * DH + n0 + c8)
            = *(const uint4*)(&ols[r][c8]);
    }
}

// ------------------------------------------------------------ K5: out = ao@Wo+bo
__global__ __launch_bounds__(256) void k_out(
    const u16t* __restrict__ ao, const u16t* __restrict__ WoT,
    const float* __restrict__ bo, float* __restrict__ out)
{
    __shared__ __align__(16) u16t sm[10240];
    u16t* Als = sm;
    u16t* Bls = sm + 8192;
    int m0 = blockIdx.y * 128, n0 = blockIdx.x * 32;
    const u16t* A = ao + (size_t)m0 * D_SZ;
    const u16t* Bt = WoT + (size_t)n0 * D_SZ;
    f32x4 acc[2][2] = {};
    gemm_mainloop<2>(A, D_SZ, Bt, D_SZ, D_SZ, threadIdx.x, Als, Bls, acc);
    int w = threadIdx.x >> 6, lane = threadIdx.x & 63, lr = lane & 15, kg = lane >> 4;
    __syncthreads();
    float (*ols)[36] = (float(*)[36])sm;
#pragma unroll
    for (int fi = 0; fi < 2; ++fi)
#pragma unroll
        for (int fj = 0; fj < 2; ++fj)
#pragma unroll
            for (int rr = 0; rr < 4; ++rr) {
                int rl = w * 32 + fi * 16 + kg * 4 + rr;
                ols[rl][fj * 16 + lr] = acc[fi][fj][rr] + bo[n0 + fj * 16 + lr];
            }
    __syncthreads();
    int c4 = (threadIdx.x & 7) * 4, r0 = threadIdx.x >> 3;
#pragma unroll
    for (int p = 0; p < 4; ++p) {
        int r = r0 + p * 32;
        *(float4*)(out + (size_t)(m0 + r) * D_SZ + n0 + c4) = *(const float4*)(&ols[r][c4]);
    }
}

// ---------------------------------------------------------------------- host
extern "C" void kernel_launch(void* const* d_in, const int* in_sizes, int n_in,
                              void* d_out, int out_size, void* d_ws, size_t ws_size,
                              hipStream_t stream)
{
    const float* x  = (const float*)d_in[0];
    const float* Wq = (const float*)d_in[1];
    const float* Wk = (const float*)d_in[2];
    const float* Wv = (const float*)d_in[3];
    const float* Wo = (const float*)d_in[4];
    const float* bo = (const float*)d_in[5];
    const float* W1 = (const float*)d_in[6];
    const float* b1 = (const float*)d_in[7];
    const float* W2 = (const float*)d_in[8];
    const float* b2 = (const float*)d_in[9];
    float* out = (float*)d_out;

    // workspace carve (all 256B-aligned)
    char* ws = (char*)d_ws;
    size_t off = 0;
    auto carve = [&](size_t bytes) { void* p = ws + off; off += (bytes + 255) & ~(size_t)255; return p; };
    u16t* xb   = (u16t*)carve((size_t)2048 * 512 * 2);
    u16t* xl   = (u16t*)carve((size_t)2048 * 512 * 2);
    u16t* WT   = (u16t*)carve((size_t)4 * 512 * 512 * 2);
    u16t* qb   = (u16t*)carve((size_t)2048 * 512 * 2);
    u16t* kb   = (u16t*)carve((size_t)2048 * 512 * 2);
    u16t* vT   = (u16t*)carve((size_t)2 * 512 * 1024 * 2);
    float* Beff = (float*)carve((size_t)512 * 256 * 4);
    float* a   = (float*)carve((size_t)2048 * 128 * 4);
    float* c   = (float*)carve((size_t)2048 * 128 * 4);
    unsigned char* maskb = (unsigned char*)carve((size_t)2 * 1024 * 1024);
    u16t* P    = (u16t*)carve((size_t)4 * 1024 * 1024 * 2);
    float* lpart = (float*)carve((size_t)16 * 4 * 1024 * 4);
    u16t* ao   = (u16t*)carve((size_t)2048 * 512 * 2);
    (void)ws_size;

    k_prep<<<dim3(2560), dim3(256), 0, stream>>>(x, Wq, Wk, Wv, Wo, W1, xb, xl, WT, Beff);
    k_ac<<<dim3(16, 8), dim3(256), 0, stream>>>(xb, xl, Beff, b1, a, c);
    k_qkvmask<<<dim3(896), dim3(256), 0, stream>>>(xb, WT, a, c, W2, b2, qb, kb, vT, maskb);
    k_scores<<<dim3(16, 8, 4), dim3(256), 0, stream>>>(qb, kb, maskb, P, lpart);
    k_pv<<<dim3(8, 8, 4), dim3(256), 0, stream>>>(P, vT, lpart, ao);
    k_out<<<dim3(16, 16), dim3(256), 0, stream>>>(ao, WT + (size_t)3 * 512 * 512, bo, out);
}